// Round 7
// baseline (233.127 us; speedup 1.0000x reference)
//
#include <hip/hip_runtime.h>

// VQ-VAE forward: x [64,64,32,32] f32 (NCHW, C==D), weight [512,64] f32.
// d_out: loss (1) | q_out (4194304, NCHW) | encodings (33554432, [N,K]).
//
// R17 = R16's barrier-free-drift structure + R10's EXACT dist metric.
// R16 failed (encodings absmax 1.0, q/loss pass => wrong argmin index):
// dropping x2 changed comparison precision -- reference metric sits at
// scale ~64 (ulp 7.6e-6) and quantizes near-ties that the x2-free metric
// resolves differently. Restored: per-row x2l (same ascending-d
// mul-then-add chain) and dist = (x2 + e2) - 2*dot, chain bit-identical
// to R10 (passing). Structure kept from R16:
//  - LDS: xs (32KB) + TWO 40KB W slots + e2 (2KB) + x2l -> 1 block/CU,
//    4 waves, launch_bounds(256,1); two barrier-free 2-chunk spans
//    (chunks {0,1}, restage, {2,3}); waves drift -> no lockstep
//    LDS-burst/stall oscillation (R10/R15's ~50%-per-pipe signature).
//  - wave-rotated slot order (start slot = wv&1) + explicit (==, k<)
//    tie-break (order-independent => rotation safe).
//  - e2 in LDS -> spans have NO global loads/vmcnt waits -> in-loop
//    one-hot ZERO-PREFILL is fire-and-forget; 1.0-scatter after the
//    idxf barrier (vmcnt(0)-drain orders it; proven R14/R15).

#define NROWS 65536
#define DIM 64
#define KCODES 512
#define HW 1024
#define TPB 256
#define RPB 128                     // rows per block
#define NBLOCKS (NROWS / RPB)       // 512

// d_ws float offsets
#define WT_OFF 0                    // wTp [32 dpair][512 k][2] = 32768 floats
#define E2_OFF 32768                // e2 [512]
#define PART_OFF 98816              // partials [512]

// dynamic LDS float offsets
#define XS 0                        // xs: 32 dp x 128 rows x (E,O) = 8192
#define WSL 8192                    // 2 W slots x (32 dp x 16 kg x 20) = 20480
#define ESL 28672                   // e2 copy [512]
#define X2L 29184                   // x2 per row [128]
#define DYN_FLOATS 29312
#define DYN_BYTES (DYN_FLOATS * 4)  // 117248 B -> 1 block/CU

typedef float v2f __attribute__((ext_vector_type(2)));
typedef float v4f __attribute__((ext_vector_type(4)));

__global__ __launch_bounds__(256) void vq_prep(
    const float* __restrict__ w, float* __restrict__ ws)
{
    // w -> wTp[dpair][k][2] (E,O interleave) + e2 (ascending-d chain)
    const int k = blockIdx.x * 256 + threadIdx.x;
    float s = 0.0f;
    for (int d = 0; d < DIM; ++d) {
        const float v = w[k * DIM + d];
        ws[WT_OFF + (d >> 1) * (KCODES * 2) + k * 2 + (d & 1)] = v;
        s = __fadd_rn(s, __fmul_rn(v, v));
    }
    ws[E2_OFF + k] = s;
}

// stage W chunk c (128 codes) into LDS slot sl: 8 v4f per thread,
// identical value mapping to R10's staging.
__device__ __forceinline__ void stage_w(
    float* smem, const float* ws, int c, int sl, int t)
{
    const float* src = ws + WT_OFF + c * 256;
    v4f tmp[8];
    #pragma unroll
    for (int i = 0; i < 8; ++i) {
        const int s = i * 1024 + t * 4;
        tmp[i] = *(const v4f*)(src + (s >> 8) * 1024 + (s & 255));
    }
    #pragma unroll
    for (int i = 0; i < 8; ++i) {
        const int s   = i * 1024 + t * 4;
        const int dp  = s >> 8;
        const int lc0 = (s & 255) >> 1;
        *(v4f*)(smem + WSL + sl * 10240 + dp * 320 + (lc0 >> 3) * 20
                + (lc0 & 7) * 2) = tmp[i];
    }
}

__global__ __launch_bounds__(TPB, 1) void vq_main(
    const float* __restrict__ x, const float* __restrict__ w,
    const float* __restrict__ ws, float* __restrict__ out,
    float* __restrict__ partial)
{
    extern __shared__ __align__(16) float smem[];
    __shared__ int   idxf[RPB];
    __shared__ float lred[4];

    const int t    = threadIdx.x;
    const int lane = t & 63;
    const int wv   = __builtin_amdgcn_readfirstlane(t >> 6);
    const int rg   = lane >> 4;       // 0..3: rows wv*32 + rg*8 .. +7
    const int kg   = lane & 15;       // 16 groups x 8 codes per chunk
    const int n0   = blockIdx.x * RPB;
    const int b    = n0 >> 10;        // 1024 % 128 == 0: no b straddle
    const int hw0  = n0 & 1023;

    // ---- encodings slab: peel zeros (floats 0..2 and last); the 16383
    // aligned v4f zeros are issued INSIDE the barrier-free dp loops.
    float* slab = out + 1 + (size_t)NROWS * DIM + (size_t)n0 * KCODES;
    v4f* s4 = (v4f*)(slab + 3);                   // 16B-aligned
    const v4f zf = (v4f){0.0f, 0.0f, 0.0f, 0.0f};
    if (t < 3) slab[t] = 0.0f;
    if (t == 4) slab[RPB * KCODES - 1] = 0.0f;

    // ---- stage x tile (128 rows) into LDS, (E,O) interleaved, unpadded:
    // xs[dp*256 + (row>>3)*16 + (row&7)*2 (+1 for odd d)]
    #pragma unroll
    for (int i = 0; i < 4; ++i) {
        const int task = i * 256 + t;          // 1024 tasks
        const int dp   = task >> 5;
        const int row4 = (task & 31) * 4;
        const float* pe = x + (size_t)(b * DIM + 2 * dp) * HW + hw0 + row4;
        const v4f xe = *(const v4f*)pe;        // 4 rows, even depth
        const v4f xo = *(const v4f*)(pe + HW); // 4 rows, odd depth
        float* dst = smem + dp * 256 + (row4 >> 3) * 16 + (row4 & 7) * 2;
        *(v4f*)dst       = (v4f){xe.x, xo.x, xe.y, xo.y};
        *(v4f*)(dst + 4) = (v4f){xe.z, xo.z, xe.w, xo.w};
    }

    // ---- stage W chunks 0,1 into slots 0,1; e2 -> LDS
    stage_w(smem, ws, 0, 0, t);
    stage_w(smem, ws, 1, 1, t);
    if (t < RPB)
        *(v4f*)(smem + ESL + t * 4) = *(const v4f*)(ws + E2_OFF + t * 4);

    __syncthreads();   // B1: xs + W01 + e2l visible

    // ---- x2 per row from LDS: same ascending-d mul-then-add chain as
    // prep's (R10's exact chain; REQUIRED for ref-matching argmin)
    if (t < RPB) {
        const float* xb = smem + (t >> 3) * 16 + (t & 7) * 2;
        float s = 0.0f;
        #pragma unroll 8
        for (int dp = 0; dp < 32; ++dp) {
            const v2f p = *(const v2f*)(xb + dp * 256);   // (E,O) of d=2dp
            s = __fadd_rn(s, __fmul_rn(p[0], p[0]));
            s = __fadd_rn(s, __fmul_rn(p[1], p[1]));
        }
        smem[X2L + t] = s;
    }
    __syncthreads();   // B1b: x2l visible

    const int cj   = wv * 4 + rg;              // x row-chunk id (0..15)
    const int rloc = wv * 32 + rg * 8;         // first row (block-local)
    const int rot  = wv & 1;                   // per-wave slot rotation
    const v4f x2a = *(const v4f*)(smem + X2L + rloc);
    const v4f x2b = *(const v4f*)(smem + X2L + rloc + 4);

    float best[8];
    int   bidx[8];
    #pragma unroll
    for (int r = 0; r < 8; ++r) { best[r] = 3.4e38f; bidx[r] = 0; }

    // ---- 2 halves x 2 chunks; spans are barrier-free: only LDS reads,
    // VALU, and fire-and-forget zero stores (no vmcnt waits inside).
    #pragma unroll 1
    for (int half = 0; half < 2; ++half) {
        if (half == 1) {
            __syncthreads();                   // B2: W01 reads done
            stage_w(smem, ws, 2, 0, t);        // restage (L2-hot, isolated)
            stage_w(smem, ws, 3, 1, t);
            __syncthreads();                   // B3: W23 visible
        }
        #pragma unroll 1
        for (int cc = 0; cc < 2; ++cc) {
            const int sl = rot ^ cc;           // slot 0/1, wave-rotated
            const int c  = half * 2 + sl;      // chunk id (slot == c&1)

            v2f acc[8][8];
            #pragma unroll
            for (int r = 0; r < 8; ++r)
                #pragma unroll
                for (int c8 = 0; c8 < 8; ++c8) acc[r][c8] = (v2f){0.f, 0.f};

            const float* xp = smem + cj * 16;
            const float* wp = smem + WSL + sl * 10240 + kg * 20;
            const int fb = c * 4096 + t;       // this chunk's prefill share
            #pragma unroll 4
            for (int dp = 0; dp < 32; ++dp) {
                const v4f X0 = *(const v4f*)(xp);        // rows 0,1 (E,O)
                const v4f X1 = *(const v4f*)(xp + 4);    // rows 2,3
                const v4f X2 = *(const v4f*)(xp + 8);    // rows 4,5
                const v4f X3 = *(const v4f*)(xp + 12);   // rows 6,7
                const v4f W0 = *(const v4f*)(wp);        // codes 0,1 (E,O)
                const v4f W1 = *(const v4f*)(wp + 4);    // codes 2,3
                const v4f W2 = *(const v4f*)(wp + 8);    // codes 4,5
                const v4f W3 = *(const v4f*)(wp + 12);   // codes 6,7
                if ((dp & 1) == 0) {           // fire-and-forget zero v4f
                    const int f = fb + ((dp >> 1) << 8);
                    if (f < 16383) s4[f] = zf;
                }
                const v2f xr[8] = {X0.xy, X0.zw, X1.xy, X1.zw,
                                   X2.xy, X2.zw, X3.xy, X3.zw};
                const v2f wc[8] = {W0.xy, W0.zw, W1.xy, W1.zw,
                                   W2.xy, W2.zw, W3.xy, W3.zw};
                #pragma unroll
                for (int r = 0; r < 8; ++r)
                    #pragma unroll
                    for (int c8 = 0; c8 < 8; ++c8)
                        acc[r][c8] += xr[r] * wc[c8];   // v_pk_fma_f32
                xp += 256;
                wp += 320;
            }

            const int kb = c * 128 + kg * 8;             // lane's 8 codes
            const v4f e20 = *(const v4f*)(smem + ESL + kb);
            const v4f e21 = *(const v4f*)(smem + ESL + kb + 4);
            #pragma unroll
            for (int r = 0; r < 8; ++r) {
                const float x2r = (r < 4) ? x2a[r] : x2b[r - 4];
                #pragma unroll
                for (int c8 = 0; c8 < 8; ++c8) {
                    const float dot  = acc[r][c8][0] + acc[r][c8][1]; // E+O
                    const float e2c  = (c8 < 4) ? e20[c8] : e21[c8 - 4];
                    const float dist = __fsub_rn(__fadd_rn(x2r, e2c),
                                                 __fmul_rn(2.0f, dot));
                    const int   k    = kb + c8;
                    if (dist < best[r] ||
                        (dist == best[r] && k < bidx[r])) {
                        best[r] = dist; bidx[r] = k;
                    }
                }
            }
        }
    }

    // ---- kg butterfly (16 lanes); explicit lowest-index tie-break
    #pragma unroll
    for (int m = 1; m <= 8; m <<= 1) {
        #pragma unroll
        for (int r = 0; r < 8; ++r) {
            const float ob = __shfl_xor(best[r], m, 64);
            const int   oi = __shfl_xor(bidx[r], m, 64);
            if (ob < best[r] || (ob == best[r] && oi < bidx[r])) {
                best[r] = ob; bidx[r] = oi;
            }
        }
    }
    if (kg == 0) {
        #pragma unroll
        for (int r = 0; r < 8; ++r)
            idxf[rloc + r] = bidx[r];
    }
    __syncthreads();   // B4: idxf visible; vmcnt(0) drain commits prefill

    // ---- one-hot scatter: ordered after prefill by B4's drain
    if (t < RPB)
        slab[(size_t)t * KCODES + idxf[t]] = 1.0f;

    // ---- epilogue: q gather/store + loss; x read from LDS (same values).
    const int rt = t & 127;
    const int dg = t >> 7;            // 2 groups x 32 d (16 dp pairs)
    const int widx = idxf[rt];
    const float* wrow = w + widx * DIM + dg * 32;
    const float* xb = smem + dg * 16 * 256 + (rt >> 3) * 16 + (rt & 7) * 2;
    float* q = out + 1;
    float lsum = 0.0f;
    #pragma unroll
    for (int jj = 0; jj < 16; ++jj) {
        const int dE = dg * 32 + 2 * jj;
        const v2f wp2 = *(const v2f*)(wrow + 2 * jj);     // per-lane, L1-hot
        const v2f xp2 = *(const v2f*)(xb + jj * 256);     // (E,O) from LDS
        const float dfE = __fsub_rn(wp2[0], xp2[0]);      // d ascending: E,O
        lsum = __fadd_rn(lsum, __fmul_rn(dfE, dfE));
        const float dfO = __fsub_rn(wp2[1], xp2[1]);
        lsum = __fadd_rn(lsum, __fmul_rn(dfO, dfO));
        q[(size_t)(b * DIM + dE) * HW + hw0 + rt]     = wp2[0];
        q[(size_t)(b * DIM + dE + 1) * HW + hw0 + rt] = wp2[1];
    }

    #pragma unroll
    for (int off = 32; off; off >>= 1) lsum += __shfl_down(lsum, off, 64);
    if (lane == 0) lred[wv] = lsum;
    __syncthreads();
    if (t == 0)
        partial[blockIdx.x] = (lred[0] + lred[1]) + (lred[2] + lred[3]);
}

__global__ __launch_bounds__(256) void vq_final(
    const float* __restrict__ partial, float* __restrict__ out)
{
    __shared__ float s[256];
    const int t = threadIdx.x;
    s[t] = partial[t] + partial[t + 256];
    __syncthreads();
    for (int off = 128; off; off >>= 1) {
        if (t < off) s[t] += s[t + off];
        __syncthreads();
    }
    if (t == 0) {
        const float m = s[0] / 4194304.0f;            // mean over B*H*W*D
        out[0] = __fadd_rn(m, __fmul_rn(0.25f, m));   // z_q + 0.25*z_e
    }
}

extern "C" void kernel_launch(void* const* d_in, const int* in_sizes, int n_in,
                              void* d_out, int out_size, void* d_ws, size_t ws_size,
                              hipStream_t stream) {
    const float* x = (const float*)d_in[0];
    const float* w = (const float*)d_in[1];
    float* out     = (float*)d_out;
    float* ws      = (float*)d_ws;

    // 117248 B dynamic LDS > 64 KB default limit: opt in (host-side,
    // idempotent, graph-capture-safe — not a stream op).
    (void)hipFuncSetAttribute((const void*)vq_main,
                              hipFuncAttributeMaxDynamicSharedMemorySize,
                              DYN_BYTES);

    vq_prep<<<2, 256, 0, stream>>>(w, ws);
    vq_main<<<NBLOCKS, TPB, DYN_BYTES, stream>>>(x, w, ws, out, ws + PART_OFF);
    vq_final<<<1, 256, 0, stream>>>(ws + PART_OFF, out);
}

// Round 8
// 222.816 us; speedup vs baseline: 1.0463x; 1.0463x over previous
//
#include <hip/hip_runtime.h>

// VQ-VAE forward: x [64,64,32,32] f32 (NCHW, C==D), weight [512,64] f32.
// d_out: loss (1) | q_out (4194304, NCHW) | encodings (33554432, [N,K]).
//
// R18 = R10 byte-for-byte (proven 89.6us: both operands LDS, 4 waves x
// 128 rows, 4 code-chunks, double-buffered W staging, barriers) with ONE
// change: the one-hot zero-fill moves from the serial ~20us tail into the
// dp loop as fire-and-forget stores (1 v4f per 2 dp per thread; same
// 16383-v4f coverage), tail replaced by a single 1.0-scatter.
// Why this placement is safe where R14/R15 regressed:
//  - R14: dp loop had global W loads -> compiler vmcnt waits before each
//    W use swept the ordered store queue -> serialized. R10's dp loop has
//    ZERO global loads -> no vmcnt waits inside -> stores fire-and-forget.
//  - R15: 64KB bursts issued immediately before staging barriers -> the
//    barrier's vmcnt(0) drain stalled on them. Here stores spread over
//    ~4000 cyc/chunk; by each barrier they are already retired to L2.
//  - prefill < scatter ordering via the post-argmin barrier's vmcnt(0)
//    drain (same scheme passed in R14/R15/R17).
// Dist arithmetic + tie order bit-identical to R6..R10 (passing).

#define NROWS 65536
#define DIM 64
#define KCODES 512
#define HW 1024
#define TPB 256
#define RPB 128                     // rows per block
#define NBLOCKS (NROWS / RPB)       // 512

// d_ws float offsets
#define WT_OFF 0                    // wTp [32 dpair][512 k][2] = 32768 floats
#define E2_OFF 32768                // e2 [512]
#define PART_OFF 98816              // partials [512]

// dynamic LDS float offsets
#define XW 8192                     // xs: 32 dp x 128 rows x (E,O)
#define DYN_FLOATS (XW + 32 * 320)  // + w chunk 32 dp x (16 kg x 20) = 18432
#define DYN_BYTES (DYN_FLOATS * 4)  // 73728 B

typedef float v2f __attribute__((ext_vector_type(2)));
typedef float v4f __attribute__((ext_vector_type(4)));

__global__ __launch_bounds__(256) void vq_prep(
    const float* __restrict__ w, float* __restrict__ ws)
{
    // w -> wTp[dpair][k][2] (E,O interleave) + e2 (ascending-d chain)
    const int k = blockIdx.x * 256 + threadIdx.x;
    float s = 0.0f;
    for (int d = 0; d < DIM; ++d) {
        const float v = w[k * DIM + d];
        ws[WT_OFF + (d >> 1) * (KCODES * 2) + k * 2 + (d & 1)] = v;
        s = __fadd_rn(s, __fmul_rn(v, v));
    }
    ws[E2_OFF + k] = s;
}

__global__ __launch_bounds__(TPB) void vq_main(
    const float* __restrict__ x, const float* __restrict__ w,
    const float* __restrict__ ws, float* __restrict__ out,
    float* __restrict__ partial)
{
    extern __shared__ __align__(16) float smem[];   // [0,XW)=xs, [XW..)=wl
    __shared__ int   idxf[RPB];
    __shared__ float x2l[RPB];
    __shared__ float lred[4];

    const int t    = threadIdx.x;
    const int lane = t & 63;
    const int wv   = __builtin_amdgcn_readfirstlane(t >> 6);
    const int rg   = lane >> 4;       // 0..3: rows wv*32 + rg*8 .. +7
    const int kg   = lane & 15;       // 16 groups x 8 codes per chunk
    const int n0   = blockIdx.x * RPB;
    const int b    = n0 >> 10;        // 1024 % 128 == 0: no b straddle
    const int hw0  = n0 & 1023;

    // ---- encodings slab: peel zeros (floats 0..2 and last); the 16383
    // aligned v4f zeros are issued inside the dp loops (fire-and-forget).
    float* slab = out + 1 + (size_t)NROWS * DIM + (size_t)n0 * KCODES;
    v4f* s4 = (v4f*)(slab + 3);                   // 16B-aligned
    const v4f zf = (v4f){0.0f, 0.0f, 0.0f, 0.0f};
    if (t < 3) slab[t] = 0.0f;
    if (t == 4) slab[RPB * KCODES - 1] = 0.0f;

    // ---- prefetch w chunk 0 into staging regs (independent of xs staging)
    v4f wstg[8];
    {
        const float* src = ws + WT_OFF;
        #pragma unroll
        for (int i = 0; i < 8; ++i) {
            const int s = i * 1024 + t * 4;
            wstg[i] = *(const v4f*)(src + (s >> 8) * 1024 + (s & 255));
        }
    }

    // ---- stage x tile (128 rows) into LDS, (E,O) interleaved, unpadded:
    // xs[dp*256 + (row>>3)*16 + (row&7)*2 (+1 for odd d)]
    #pragma unroll
    for (int i = 0; i < 4; ++i) {
        const int task = i * 256 + t;          // 1024 tasks
        const int dp   = task >> 5;
        const int row4 = (task & 31) * 4;
        const float* pe = x + (size_t)(b * DIM + 2 * dp) * HW + hw0 + row4;
        const v4f xe = *(const v4f*)pe;        // 4 rows, even depth
        const v4f xo = *(const v4f*)(pe + HW); // 4 rows, odd depth
        float* dst = smem + dp * 256 + (row4 >> 3) * 16 + (row4 & 7) * 2;
        *(v4f*)dst       = (v4f){xe.x, xo.x, xe.y, xo.y};
        *(v4f*)(dst + 4) = (v4f){xe.z, xo.z, xe.w, xo.w};
    }
    __syncthreads();   // xs visible

    // ---- x2 per row from LDS: same ascending-d mul-then-add chain as prep's
    if (t < RPB) {
        const float* xb = smem + (t >> 3) * 16 + (t & 7) * 2;
        float s = 0.0f;
        #pragma unroll 8
        for (int dp = 0; dp < 32; ++dp) {
            const v2f p = *(const v2f*)(xb + dp * 256);   // (E,O) of d=2dp
            s = __fadd_rn(s, __fmul_rn(p[0], p[0]));
            s = __fadd_rn(s, __fmul_rn(p[1], p[1]));
        }
        x2l[t] = s;
    }

    // ---- write w chunk 0 to LDS; prefetch chunk 1
    #pragma unroll
    for (int i = 0; i < 8; ++i) {
        const int s   = i * 1024 + t * 4;
        const int dp  = s >> 8;
        const int lc0 = (s & 255) >> 1;
        *(v4f*)(smem + XW + dp * 320 + (lc0 >> 3) * 20 + (lc0 & 7) * 2)
            = wstg[i];
    }
    {
        const float* src = ws + WT_OFF + 256;
        #pragma unroll
        for (int i = 0; i < 8; ++i) {
            const int s = i * 1024 + t * 4;
            wstg[i] = *(const v4f*)(src + (s >> 8) * 1024 + (s & 255));
        }
    }
    __syncthreads();   // x2l + w chunk 0 visible

    const float* e2p = ws + E2_OFF;
    const int cj = wv * 4 + rg;                // x row-chunk id (0..15)
    const int rloc = wv * 32 + rg * 8;         // first row (block-local)
    const v4f x2a = *(const v4f*)(x2l + rloc);
    const v4f x2b = *(const v4f*)(x2l + rloc + 4);

    float best[8];
    int   bidx[8];
    #pragma unroll
    for (int r = 0; r < 8; ++r) { best[r] = 3.4e38f; bidx[r] = 0; }

    // ---- 4 chunks of 128 codes, ascending (=> per-lane k ascending)
    #pragma unroll 1
    for (int c = 0; c < 4; ++c) {
        v2f acc[8][8];
        #pragma unroll
        for (int r = 0; r < 8; ++r)
            #pragma unroll
            for (int cc = 0; cc < 8; ++cc) acc[r][cc] = (v2f){0.f, 0.f};

        const float* xp = smem + cj * 16;
        const float* wp = smem + XW + kg * 20;
        const int fb = c * 4096 + t;           // this chunk's prefill share
        #pragma unroll 4
        for (int dp = 0; dp < 32; ++dp) {
            const v4f X0 = *(const v4f*)(xp);        // rows 0,1 (E,O) pairs
            const v4f X1 = *(const v4f*)(xp + 4);    // rows 2,3
            const v4f X2 = *(const v4f*)(xp + 8);    // rows 4,5
            const v4f X3 = *(const v4f*)(xp + 12);   // rows 6,7
            const v4f W0 = *(const v4f*)(wp);        // codes 0,1 (E,O) pairs
            const v4f W1 = *(const v4f*)(wp + 4);    // codes 2,3
            const v4f W2 = *(const v4f*)(wp + 8);    // codes 4,5
            const v4f W3 = *(const v4f*)(wp + 12);   // codes 6,7
            if ((dp & 1) == 0) {               // fire-and-forget zero v4f:
                const int f = fb + ((dp >> 1) << 8);   // no global LOADS in
                if (f < 16383) s4[f] = zf;     // this loop -> no vmcnt waits
            }
            const v2f xr[8] = {X0.xy, X0.zw, X1.xy, X1.zw,
                               X2.xy, X2.zw, X3.xy, X3.zw};
            const v2f wc[8] = {W0.xy, W0.zw, W1.xy, W1.zw,
                               W2.xy, W2.zw, W3.xy, W3.zw};
            #pragma unroll
            for (int r = 0; r < 8; ++r)
                #pragma unroll
                for (int cc = 0; cc < 8; ++cc)
                    acc[r][cc] += xr[r] * wc[cc];    // v_pk_fma_f32 (E,O)
            xp += 256;
            wp += 320;
        }

        const int kb = c * 128 + kg * 8;             // lane's 8 codes
        const v4f e20 = *(const v4f*)(e2p + kb);
        const v4f e21 = *(const v4f*)(e2p + kb + 4);
        #pragma unroll
        for (int r = 0; r < 8; ++r) {
            const float x2r = (r < 4) ? x2a[r] : x2b[r - 4];
            #pragma unroll
            for (int cc = 0; cc < 8; ++cc) {         // cc ascending: first-min
                const float dot  = acc[r][cc][0] + acc[r][cc][1];   // E + O
                const float e2c  = (cc < 4) ? e20[cc] : e21[cc - 4];
                const float dist = __fsub_rn(__fadd_rn(x2r, e2c),
                                             __fmul_rn(2.0f, dot));
                if (dist < best[r]) { best[r] = dist; bidx[r] = kb + cc; }
            }
        }

        if (c < 3) {
            __syncthreads();   // all reads of w chunk c done
            #pragma unroll
            for (int i = 0; i < 8; ++i) {            // write chunk c+1
                const int s   = i * 1024 + t * 4;
                const int dp  = s >> 8;
                const int lc0 = (s & 255) >> 1;
                *(v4f*)(smem + XW + dp * 320 + (lc0 >> 3) * 20
                        + (lc0 & 7) * 2) = wstg[i];
            }
            if (c < 2) {                             // prefetch chunk c+2
                const float* src = ws + WT_OFF + (c + 2) * 256;
                #pragma unroll
                for (int i = 0; i < 8; ++i) {
                    const int s = i * 1024 + t * 4;
                    wstg[i] = *(const v4f*)(src + (s >> 8) * 1024 + (s & 255));
                }
            }
            __syncthreads();   // chunk c+1 visible
        }
    }

    // ---- kg butterfly (16 lanes); explicit lowest-index tie-break
    #pragma unroll
    for (int m = 1; m <= 8; m <<= 1) {
        #pragma unroll
        for (int r = 0; r < 8; ++r) {
            const float ob = __shfl_xor(best[r], m, 64);
            const int   oi = __shfl_xor(bidx[r], m, 64);
            if (ob < best[r] || (ob == best[r] && oi < bidx[r])) {
                best[r] = ob; bidx[r] = oi;
            }
        }
    }
    if (kg == 0) {
        #pragma unroll
        for (int r = 0; r < 8; ++r)
            idxf[rloc + r] = bidx[r];
    }
    __syncthreads();   // idxf visible; vmcnt(0) drain commits ALL prefill

    // ---- one-hot scatter: ordered after prefill by the barrier's drain
    if (t < RPB)
        slab[(size_t)t * KCODES + idxf[t]] = 1.0f;

    // ---- epilogue: q gather/store + loss; x read from LDS (same values).
    const int rt = t & 127;
    const int dg = t >> 7;            // 2 groups x 32 d (16 dp pairs)
    const int widx = idxf[rt];
    const float* wrow = w + widx * DIM + dg * 32;
    const float* xb = smem + dg * 16 * 256 + (rt >> 3) * 16 + (rt & 7) * 2;
    float* q = out + 1;
    float lsum = 0.0f;
    #pragma unroll
    for (int jj = 0; jj < 16; ++jj) {
        const int dE = dg * 32 + 2 * jj;
        const v2f wp2 = *(const v2f*)(wrow + 2 * jj);     // per-lane, L1-hot
        const v2f xp2 = *(const v2f*)(xb + jj * 256);     // (E,O) from LDS
        const float dfE = __fsub_rn(wp2[0], xp2[0]);      // d ascending: E,O
        lsum = __fadd_rn(lsum, __fmul_rn(dfE, dfE));
        const float dfO = __fsub_rn(wp2[1], xp2[1]);
        lsum = __fadd_rn(lsum, __fmul_rn(dfO, dfO));
        q[(size_t)(b * DIM + dE) * HW + hw0 + rt]     = wp2[0];
        q[(size_t)(b * DIM + dE + 1) * HW + hw0 + rt] = wp2[1];
    }

    #pragma unroll
    for (int off = 32; off; off >>= 1) lsum += __shfl_down(lsum, off, 64);
    if (lane == 0) lred[wv] = lsum;
    __syncthreads();
    if (t == 0)
        partial[blockIdx.x] = (lred[0] + lred[1]) + (lred[2] + lred[3]);
}

__global__ __launch_bounds__(256) void vq_final(
    const float* __restrict__ partial, float* __restrict__ out)
{
    __shared__ float s[256];
    const int t = threadIdx.x;
    s[t] = partial[t] + partial[t + 256];
    __syncthreads();
    for (int off = 128; off; off >>= 1) {
        if (t < off) s[t] += s[t + off];
        __syncthreads();
    }
    if (t == 0) {
        const float m = s[0] / 4194304.0f;            // mean over B*H*W*D
        out[0] = __fadd_rn(m, __fmul_rn(0.25f, m));   // z_q + 0.25*z_e
    }
}

extern "C" void kernel_launch(void* const* d_in, const int* in_sizes, int n_in,
                              void* d_out, int out_size, void* d_ws, size_t ws_size,
                              hipStream_t stream) {
    const float* x = (const float*)d_in[0];
    const float* w = (const float*)d_in[1];
    float* out     = (float*)d_out;
    float* ws      = (float*)d_ws;

    // 73728 B dynamic LDS > 64 KB default limit: opt in (host-side,
    // idempotent, graph-capture-safe — not a stream op).
    (void)hipFuncSetAttribute((const void*)vq_main,
                              hipFuncAttributeMaxDynamicSharedMemorySize,
                              DYN_BYTES);

    vq_prep<<<2, 256, 0, stream>>>(w, ws);
    vq_main<<<NBLOCKS, TPB, DYN_BYTES, stream>>>(x, w, ws, out, ws + PART_OFF);
    vq_final<<<1, 256, 0, stream>>>(ws + PART_OFF, out);
}